// Round 2
// baseline (600.208 us; speedup 1.0000x reference)
//
#include <hip/hip_runtime.h>
#include <hip/hip_bf16.h>

#define TOKS 16384
#define HID  4096
#define NEXP 64
#define TOKB 64     // tokens per block
#define BH   64     // h-chunk staged in LDS (doubles)
#define XSTR 66     // 66*8B=528B row stride: 16B-aligned, 2-way-max bank pattern on b128 reads
#define LSTR 65

// d_ws layout: [0, 2MB) = W converted to fp64; then 128 floats of reduction slots:
//   wsf[0..63] = sum of probs per expert, wsf[64..127] = argmax counts per expert

__global__ void moe_w_cvt(const float* __restrict__ W, double* __restrict__ Wd) {
    const int i = blockIdx.x * blockDim.x + threadIdx.x;
    if (i < NEXP * HID) Wd[i] = (double)W[i];
}

__global__ void moe_gate_init(float* __restrict__ wsf) {
    if (threadIdx.x < 128) wsf[threadIdx.x] = 0.0f;
}

__global__ __launch_bounds__(512, 2)
void moe_gate_main(const float* __restrict__ X, const double* __restrict__ Wd,
                   float* __restrict__ out, float* __restrict__ wsf) {
    __shared__ double xs[TOKB][XSTR];
    __shared__ double L[TOKB][LSTR];

    const int tid  = threadIdx.x;
    const int lane = tid & 63;
    const int wid  = __builtin_amdgcn_readfirstlane(tid >> 6);  // 0..7, wave-uniform
    const int tok0 = blockIdx.x * TOKB;

    double acc[8] = {0., 0., 0., 0., 0., 0., 0., 0.};

    for (int h0 = 0; h0 < HID; h0 += BH) {
        // stage X[64 tok][64 h] as fp64 (cvt once, reused 64x)
        #pragma unroll
        for (int i = 0; i < 8; ++i) {
            const int li = tid + i * 512;
            const int r  = li >> 6;     // token 0..63
            const int hh = li & 63;
            xs[r][hh] = (double)X[((size_t)(tok0 + r) << 12) + (h0 + hh)];
        }
        __syncthreads();

        // lane = token; 8 wave-uniform experts -> W64 via scalar loads (SGPR operand of fma_f64)
        const double* wchunk = Wd + (((size_t)(wid << 3)) << 12) + h0;
        #pragma unroll 2
        for (int hh = 0; hh < BH; hh += 2) {
            const double2 xv = *(const double2*)&xs[lane][hh];
            #pragma unroll
            for (int e = 0; e < 8; ++e) {
                const double* wr = wchunk + (((size_t)e) << 12) + hh;
                acc[e] = fma(xv.x, wr[0], acc[e]);
                acc[e] = fma(xv.y, wr[1], acc[e]);
            }
        }
        __syncthreads();
    }

    // logits -> LDS: L[token][expert], fp64
    #pragma unroll
    for (int e = 0; e < 8; ++e) L[lane][(wid << 3) + e] = acc[e];
    __syncthreads();

    float* outIdx = out;                    // [16384*8] indices as float
    float* outW   = out + (TOKS * 8);       // [16384*8] normalized weights

    float rp = 0.0f;                        // per-lane (=expert) prob accumulator

    for (int tt = 0; tt < 8; ++tt) {
        const int t = (wid << 3) + tt;      // token within block
        const double lg = L[t][lane];       // lane = expert now
        const float lgf = (float)lg;

        // softmax over 64 experts (wave-wide); values in fp32 (2% tolerance),
        // ranking decisions in fp64 below
        float m = lgf;
        #pragma unroll
        for (int o = 32; o; o >>= 1) m = fmaxf(m, __shfl_xor(m, o, 64));
        const float p = __expf(lgf - m);
        float s = p;
        #pragma unroll
        for (int o = 32; o; o >>= 1) s += __shfl_xor(s, o, 64);
        const float inv_s = 1.0f / s;
        rp += p * inv_s;

        // top-8 on fp64 logits (exact ranking), ties -> lower index (JAX semantics)
        double v = lg;
        float wk[8]; int ik[8];
        #pragma unroll
        for (int k = 0; k < 8; ++k) {
            double bv = v; int bi = lane;
            #pragma unroll
            for (int o = 32; o; o >>= 1) {
                const double ov = __shfl_xor(bv, o, 64);
                const int    oi = __shfl_xor(bi, o, 64);
                if (ov > bv || (ov == bv && oi < bi)) { bv = ov; bi = oi; }
            }
            wk[k] = __expf((float)bv - m) * inv_s;  // winner's score
            ik[k] = bi;
            if (lane == bi) v = -1.0e300;           // exclude winner
        }

        if (lane == 0) {
            const float denom = (((wk[0]+wk[1])+(wk[2]+wk[3])) +
                                 ((wk[4]+wk[5])+(wk[6]+wk[7]))) + 1e-20f;
            const float invd = 1.0f / denom;
            const size_t base = ((size_t)(tok0 + t)) << 3;
            #pragma unroll
            for (int k = 0; k < 8; ++k) {
                outIdx[base + k] = (float)ik[k];
                outW[base + k]   = wk[k] * invd;
            }
            atomicAdd(&wsf[NEXP + ik[0]], 1.0f);    // argmax histogram
        }
    }
    atomicAdd(&wsf[lane], rp);                      // per-expert prob sums
}

__global__ void moe_gate_final(const float* __restrict__ wsf, float* __restrict__ out) {
    const int e = threadIdx.x;  // 64 threads
    float v = wsf[e] * wsf[NEXP + e];
    #pragma unroll
    for (int o = 32; o; o >>= 1) v += __shfl_xor(v, o, 64);
    if (e == 0) {
        // aux = 64 * sum_e (rps[e]/T) * (cnt[e]/T)
        out[2 * TOKS * 8] = v * (64.0f / ((float)TOKS * (float)TOKS));
    }
}

extern "C" void kernel_launch(void* const* d_in, const int* in_sizes, int n_in,
                              void* d_out, int out_size, void* d_ws, size_t ws_size,
                              hipStream_t stream) {
    const float* X = (const float*)d_in[0];   // [4,4096,4096] fp32
    const float* W = (const float*)d_in[1];   // [64,4096] fp32
    float* out = (float*)d_out;
    double* Wd = (double*)d_ws;
    float* wsf = (float*)(Wd + NEXP * HID);

    moe_w_cvt<<<(NEXP * HID + 255) / 256, 256, 0, stream>>>(W, Wd);
    moe_gate_init<<<1, 128, 0, stream>>>(wsf);
    moe_gate_main<<<TOKS / TOKB, 512, 0, stream>>>(X, Wd, out, wsf);
    moe_gate_final<<<1, 64, 0, stream>>>(wsf, out);
}

// Round 3
// 413.642 us; speedup vs baseline: 1.4510x; 1.4510x over previous
//
#include <hip/hip_runtime.h>
#include <hip/hip_bf16.h>

#define TOKS 16384
#define HID  4096
#define NEXP 64
#define TOKB 64
#define BH   128
#define XSTR 132     // 128+4 pad, 16B-aligned rows; b128 reads ~2-way max (free per m136)
#define EPS  1e-4f   // flag threshold: fp32 accum err <=~5e-6, 20x margin

// ===== main-path ws layout (floats) =====
// [0..63] prob sums | [64..127] argmax counts | int@[128] flag count |
// ints [192..192+16384) flag list | floats [16576...) partials P[kc][tok][exp]
#define WS_FLAGCNT  128
#define WS_FLAGLIST 192
#define WS_PBASE    16576

__global__ void moe_init(float* __restrict__ wsf, int n) {
    const int i = blockIdx.x * blockDim.x + threadIdx.x;
    if (i < n) wsf[i] = 0.0f;
}

// ---------- stage 1: fp32 partial GEMM, K-split via blockIdx.y ----------
__global__ __launch_bounds__(256, 4)
void moe_part(const float* __restrict__ X, const float* __restrict__ W,
              float* __restrict__ P, int klen) {
    __shared__ float xs[TOKB][XSTR];
    const int tid  = threadIdx.x;
    const int lane = tid & 63;
    const int wid  = __builtin_amdgcn_readfirstlane(tid >> 6);  // 0..3
    const int tok0 = blockIdx.x * TOKB;
    const int kc   = blockIdx.y;
    const int k0   = kc * klen;

    float acc[16];
    #pragma unroll
    for (int e = 0; e < 16; ++e) acc[e] = 0.f;

    for (int h0 = k0; h0 < k0 + klen; h0 += BH) {
        // stage X[64 tok][128 h]: wave = 2 rows of 512B, coalesced
        #pragma unroll
        for (int p = 0; p < 8; ++p) {
            const int row = (tid >> 5) + (p << 3);
            const int col = (tid & 31) << 2;
            *(float4*)&xs[row][col] =
                *(const float4*)&X[(size_t)(tok0 + row) * HID + h0 + col];
        }
        __syncthreads();

        // lane = token; 16 wave-uniform experts -> W rides the scalar path
        const float* wbase = W + (size_t)(wid * 16) * HID + h0;
        #pragma unroll 2
        for (int hh = 0; hh < BH; hh += 4) {
            const float4 xv = *(const float4*)&xs[lane][hh];
            #pragma unroll
            for (int e = 0; e < 16; ++e) {
                const float4 wv = *(const float4*)(wbase + (size_t)e * HID + hh);
                acc[e] = fmaf(xv.x, wv.x, acc[e]);
                acc[e] = fmaf(xv.y, wv.y, acc[e]);
                acc[e] = fmaf(xv.z, wv.z, acc[e]);
                acc[e] = fmaf(xv.w, wv.w, acc[e]);
            }
        }
        __syncthreads();
    }

    // transpose through LDS -> coalesced P store
    float* xsf = &xs[0][0];  // reuse as [64][68]
    #pragma unroll
    for (int e = 0; e < 16; ++e) xsf[lane * 68 + wid * 16 + e] = acc[e];
    __syncthreads();
    {
        const int tok = tid >> 2;
        const int e0  = (tid & 3) << 4;
        float* dst = P + ((size_t)kc * TOKS + tok0 + tok) * NEXP + e0;
        const float* src = xsf + tok * 68 + e0;
        #pragma unroll
        for (int q = 0; q < 4; ++q)
            *(float4*)(dst + 4 * q) = *(const float4*)(src + 4 * q);
    }
}

// ---------- stage 2: reduce partials, softmax, top-8, flag close calls ----------
template <int KS>
__global__ __launch_bounds__(256, 4)
void moe_topk(const float* __restrict__ P, float* __restrict__ out,
              float* __restrict__ wsf) {
    const int tid  = threadIdx.x;
    const int lane = tid & 63;
    const int wid  = tid >> 6;   // 0..3
    const int tok0 = blockIdx.x * TOKB;
    float* outIdx = out;
    float* outW   = out + TOKS * 8;
    int* flagcnt  = (int*)wsf + WS_FLAGCNT;
    int* flaglist = (int*)wsf + WS_FLAGLIST;

    float rp = 0.f;
    for (int tt = 0; tt < 16; ++tt) {
        const int tok = tok0 + wid * 16 + tt;
        float lg = 0.f;
        #pragma unroll
        for (int kc = 0; kc < KS; ++kc)
            lg += P[((size_t)kc * TOKS + tok) * NEXP + lane];

        // wave-wide softmax (lane = expert)
        float m = lg;
        #pragma unroll
        for (int o = 32; o; o >>= 1) m = fmaxf(m, __shfl_xor(m, o, 64));
        const float p = __expf(lg - m);
        float s = p;
        #pragma unroll
        for (int o = 32; o; o >>= 1) s += __shfl_xor(s, o, 64);
        const float inv_s = 1.0f / s;
        rp += p * inv_s;

        // top-9 (9th only for the membership-gap check), ties -> lower index
        float v = lg;
        float lw[9]; int ik[9];
        #pragma unroll
        for (int k = 0; k < 9; ++k) {
            float bv = v; int bi = lane;
            #pragma unroll
            for (int o = 32; o; o >>= 1) {
                const float ov = __shfl_xor(bv, o, 64);
                const int   oi = __shfl_xor(bi, o, 64);
                if (ov > bv || (ov == bv && oi < bi)) { bv = ov; bi = oi; }
            }
            lw[k] = bv; ik[k] = bi;
            if (lane == bi) v = -3.0e38f;
        }
        float mingap = 3.0e38f;
        #pragma unroll
        for (int k = 0; k < 8; ++k) mingap = fminf(mingap, lw[k] - lw[k + 1]);

        float wk[8]; float denom = 1e-20f;
        #pragma unroll
        for (int k = 0; k < 8; ++k) { wk[k] = __expf(lw[k] - m) * inv_s; denom += wk[k]; }
        const float invd = 1.0f / denom;
        const size_t base = (size_t)tok * 8;
        if (lane < 8) {
            outIdx[base + lane] = (float)ik[lane];
            outW[base + lane]   = wk[lane] * invd;
        }
        if (lane == 0) {
            atomicAdd(&wsf[NEXP + ik[0]], 1.0f);
            if (mingap < EPS) {
                const int pos = atomicAdd(flagcnt, 1);
                if (pos < TOKS) flaglist[pos] = tok;
            }
        }
    }
    atomicAdd(&wsf[lane], rp);
}

// ---------- stage 3: exact fp64 redo for flagged tokens ----------
__global__ __launch_bounds__(256, 2)
void moe_fix(const float* __restrict__ X, const float* __restrict__ W,
             float* __restrict__ out, float* __restrict__ wsf) {
    __shared__ double red[256];
    const int tid = threadIdx.x;
    const int e   = tid & 63;
    const int kc  = tid >> 6;
    const int nf  = min(*((int*)wsf + WS_FLAGCNT), TOKS);
    const int* flaglist = (const int*)wsf + WS_FLAGLIST;
    float* outIdx = out;
    float* outW   = out + TOKS * 8;

    for (int fi = blockIdx.x; fi < nf; fi += gridDim.x) {
        const int tok = flaglist[fi];
        const float* xrow = X + (size_t)tok * HID + kc * 1024;
        const float* wrow = W + (size_t)e  * HID + kc * 1024;
        double part = 0.0;
        for (int j = 0; j < 1024; j += 4) {
            const float4 xv = *(const float4*)(xrow + j);
            const float4 wv = *(const float4*)(wrow + j);
            part = fma((double)xv.x, (double)wv.x, part);
            part = fma((double)xv.y, (double)wv.y, part);
            part = fma((double)xv.z, (double)wv.z, part);
            part = fma((double)xv.w, (double)wv.w, part);
        }
        red[tid] = part;
        __syncthreads();
        if (tid < 64) {   // whole wave 0, lane = expert
            const double lg = ((red[tid] + red[64 + tid]) + red[128 + tid]) + red[192 + tid];
            const float lgf = (float)lg;
            float m = lgf;
            #pragma unroll
            for (int o = 32; o; o >>= 1) m = fmaxf(m, __shfl_xor(m, o, 64));
            const float p = __expf(lgf - m);
            float s = p;
            #pragma unroll
            for (int o = 32; o; o >>= 1) s += __shfl_xor(s, o, 64);
            const float inv_s = 1.0f / s;

            double v = lg;
            double bw[8]; int ik[8];
            #pragma unroll
            for (int k = 0; k < 8; ++k) {
                double bv = v; int bi = tid;
                #pragma unroll
                for (int o = 32; o; o >>= 1) {
                    const double ov = __shfl_xor(bv, o, 64);
                    const int    oi = __shfl_xor(bi, o, 64);
                    if (ov > bv || (ov == bv && oi < bi)) { bv = ov; bi = oi; }
                }
                bw[k] = bv; ik[k] = bi;
                if (tid == bi) v = -1.0e300;
            }
            float wk[8]; float denom = 1e-20f;
            #pragma unroll
            for (int k = 0; k < 8; ++k) {
                wk[k] = __expf((float)bw[k] - m) * inv_s; denom += wk[k];
            }
            const float invd = 1.0f / denom;
            const size_t base = (size_t)tok * 8;
            const int oldtop = (int)outIdx[base];   // read before overwrite
            if (tid < 8) {
                outIdx[base + tid] = (float)ik[tid];
                outW[base + tid]   = wk[tid] * invd;
            }
            if (tid == 0 && ik[0] != oldtop) {
                atomicAdd(&wsf[NEXP + oldtop], -1.0f);
                atomicAdd(&wsf[NEXP + ik[0]],  1.0f);
            }
        }
        __syncthreads();
    }
}

__global__ void moe_final(const float* __restrict__ wsf, float* __restrict__ out) {
    const int e = threadIdx.x;  // 64 threads
    float v = wsf[e] * wsf[NEXP + e];
    #pragma unroll
    for (int o = 32; o; o >>= 1) v += __shfl_xor(v, o, 64);
    if (e == 0)
        out[2 * TOKS * 8] = v * (64.0f / ((float)TOKS * (float)TOKS));
}

// ===== fallback monolith (proven R2 path) for small ws =====
__global__ void moe_w_cvt(const float* __restrict__ W, double* __restrict__ Wd) {
    const int i = blockIdx.x * blockDim.x + threadIdx.x;
    if (i < NEXP * HID) Wd[i] = (double)W[i];
}

__global__ __launch_bounds__(512, 2)
void moe_mono(const float* __restrict__ X, const double* __restrict__ Wd,
              float* __restrict__ out, float* __restrict__ wsf) {
    __shared__ double xs[TOKB][66];
    __shared__ double L[TOKB][65];
    const int tid  = threadIdx.x;
    const int lane = tid & 63;
    const int wid  = __builtin_amdgcn_readfirstlane(tid >> 6);
    const int tok0 = blockIdx.x * TOKB;
    double acc[8] = {0., 0., 0., 0., 0., 0., 0., 0.};
    for (int h0 = 0; h0 < HID; h0 += 64) {
        #pragma unroll
        for (int i = 0; i < 8; ++i) {
            const int li = tid + i * 512;
            xs[li >> 6][li & 63] = (double)X[((size_t)(tok0 + (li >> 6)) << 12) + (h0 + (li & 63))];
        }
        __syncthreads();
        const double* wchunk = Wd + (((size_t)(wid << 3)) << 12) + h0;
        #pragma unroll 2
        for (int hh = 0; hh < 64; hh += 2) {
            const double2 xv = *(const double2*)&xs[lane][hh];
            #pragma unroll
            for (int e = 0; e < 8; ++e) {
                const double* wr = wchunk + (((size_t)e) << 12) + hh;
                acc[e] = fma(xv.x, wr[0], acc[e]);
                acc[e] = fma(xv.y, wr[1], acc[e]);
            }
        }
        __syncthreads();
    }
    #pragma unroll
    for (int e = 0; e < 8; ++e) L[lane][(wid << 3) + e] = acc[e];
    __syncthreads();
    float* outIdx = out;
    float* outW   = out + (TOKS * 8);
    float rp = 0.0f;
    for (int tt = 0; tt < 8; ++tt) {
        const int t = (wid << 3) + tt;
        const double lg = L[t][lane];
        const float lgf = (float)lg;
        float m = lgf;
        #pragma unroll
        for (int o = 32; o; o >>= 1) m = fmaxf(m, __shfl_xor(m, o, 64));
        const float p = __expf(lgf - m);
        float s = p;
        #pragma unroll
        for (int o = 32; o; o >>= 1) s += __shfl_xor(s, o, 64);
        const float inv_s = 1.0f / s;
        rp += p * inv_s;
        double v = lg;
        float wk[8]; int ik[8];
        #pragma unroll
        for (int k = 0; k < 8; ++k) {
            double bv = v; int bi = lane;
            #pragma unroll
            for (int o = 32; o; o >>= 1) {
                const double ov = __shfl_xor(bv, o, 64);
                const int    oi = __shfl_xor(bi, o, 64);
                if (ov > bv || (ov == bv && oi < bi)) { bv = ov; bi = oi; }
            }
            wk[k] = __expf((float)bv - m) * inv_s; ik[k] = bi;
            if (lane == bi) v = -1.0e300;
        }
        if (lane == 0) {
            const float denom = (((wk[0]+wk[1])+(wk[2]+wk[3])) +
                                 ((wk[4]+wk[5])+(wk[6]+wk[7]))) + 1e-20f;
            const float invd = 1.0f / denom;
            const size_t base = ((size_t)(tok0 + t)) << 3;
            #pragma unroll
            for (int k = 0; k < 8; ++k) {
                outIdx[base + k] = (float)ik[k];
                outW[base + k]   = wk[k] * invd;
            }
            atomicAdd(&wsf[NEXP + ik[0]], 1.0f);
        }
    }
    atomicAdd(&wsf[lane], rp);
}

extern "C" void kernel_launch(void* const* d_in, const int* in_sizes, int n_in,
                              void* d_out, int out_size, void* d_ws, size_t ws_size,
                              hipStream_t stream) {
    const float* X = (const float*)d_in[0];   // [4,4096,4096] fp32
    const float* W = (const float*)d_in[1];   // [64,4096] fp32
    float* out = (float*)d_out;
    float* wsf = (float*)d_ws;

    int KS = 0;
    if      (ws_size >= 4ull * (WS_PBASE + 4ull * TOKS * NEXP)) KS = 4;
    else if (ws_size >= 4ull * (WS_PBASE + 2ull * TOKS * NEXP)) KS = 2;
    else if (ws_size >= 4ull * (WS_PBASE + 1ull * TOKS * NEXP)) KS = 1;

    if (KS > 0) {
        float* P = wsf + WS_PBASE;
        moe_init<<<1, 256, 0, stream>>>(wsf, 192);
        dim3 g1(TOKS / TOKB, KS);
        moe_part<<<g1, 256, 0, stream>>>(X, W, P, HID / KS);
        if (KS == 4)      moe_topk<4><<<TOKS / TOKB, 256, 0, stream>>>(P, out, wsf);
        else if (KS == 2) moe_topk<2><<<TOKS / TOKB, 256, 0, stream>>>(P, out, wsf);
        else              moe_topk<1><<<TOKS / TOKB, 256, 0, stream>>>(P, out, wsf);
        moe_fix<<<128, 256, 0, stream>>>(X, W, out, wsf);
        moe_final<<<1, 64, 0, stream>>>(wsf, out);
    } else {
        double* Wd = (double*)d_ws;
        float* wsf2 = (float*)(Wd + NEXP * HID);
        moe_w_cvt<<<(NEXP * HID + 255) / 256, 256, 0, stream>>>(W, Wd);
        moe_init<<<1, 256, 0, stream>>>(wsf2, 128);
        moe_mono<<<TOKS / TOKB, 512, 0, stream>>>(X, Wd, out, wsf2);
        moe_final<<<1, 64, 0, stream>>>(wsf2, out);
    }
}